// Round 5
// baseline (407.852 us; speedup 1.0000x reference)
//
#include <hip/hip_runtime.h>
#include <hip/hip_bf16.h>
#include <math.h>

// Problem: B=8, N=2048, DIN=DOUT=512, adj binary p=0.01
// out = tanh( D^-1/2 (A v I) D^-1/2 (X W) + b )
//
// Single persistent kernel, 1024 blocks x 256 threads (4 blocks/CU guaranteed
// by __launch_bounds__(256,4) + 24KB LDS), software grid barriers:
//   Phase A: blocks 0..63 transpose W->WT bf16; ALL blocks extract edges
//            (16 adjacency rows each, 2-deep row pipeline, 8KB/wave in flight)
//   Phase B: gemm H = X @ W. 1024 tiles of 128x64, BK=32, double-buffered,
//            A reg-staged fp32->bf16, B via global_load_lds. Panel->XCD
//            mapping keeps each X panel L2-shared across its 8 N-blocks.
//   Phase C: aggregate, batch = blk&7 -> XCD-pinned (2.1MB h slice per L2),
//            4 rows per wave, edge lists in registers via __shfl.

#define NROWS 16384
#define NCOLS 2048
#define DF    512
#define CAP   64        // max edges/row (Binom(2048,0.01): mean ~21.5, P(>=64)~0)
#define NBLK  1024

typedef __attribute__((ext_vector_type(8))) short bf16x8;
typedef __attribute__((ext_vector_type(4))) float f32x4;
typedef const void __attribute__((address_space(1))) gvoid_t;
typedef void __attribute__((address_space(3))) svoid_t;

union SM {
  struct { __hip_bfloat16 As[2][128 * 32]; __hip_bfloat16 Bs[2][64 * 32]; } g;  // 16KB + 8KB
  float t[64][65];                                                              // 16.25KB
};

// device-scope sense barrier: release (writeback) on arrive, acquire
// (invalidate) on leave. Counter pre-zeroed by hipMemsetAsync each launch.
__device__ __forceinline__ void grid_sync(int* cnt_, int tid) {
  __syncthreads();
  if (tid == 0) {
    __threadfence();   // release: writeback this XCD's L2
    __hip_atomic_fetch_add(cnt_, 1, __ATOMIC_RELAXED, __HIP_MEMORY_SCOPE_AGENT);
    while (__hip_atomic_load(cnt_, __ATOMIC_RELAXED, __HIP_MEMORY_SCOPE_AGENT) < NBLK)
      __builtin_amdgcn_s_sleep(2);
    __threadfence();   // acquire: invalidate stale L1/L2 lines
  }
  __syncthreads();
}

__global__ __launch_bounds__(256, 4) void gcn_fused(
    const float* __restrict__ X, const float* __restrict__ adj,
    const float* __restrict__ W, const float* __restrict__ bias,
    float* __restrict__ out, __hip_bfloat16* __restrict__ h,
    __hip_bfloat16* __restrict__ WT, int* __restrict__ cnt,
    int* __restrict__ edges, float* __restrict__ dinv, int* __restrict__ bar) {
  __shared__ union SM sm;
  const int blk = blockIdx.x;
  const int tid = threadIdx.x;
  const int lane = tid & 63;
  const int wv = tid >> 6;

  // ------------------------- Phase A: WT + edges -------------------------
  if (blk < 64) {                                  // W -> W^T bf16
    const int bx = blk & 7, by = blk >> 3;
    const int tx = tid & 63, ty = tid >> 6;
    #pragma unroll
    for (int i = 0; i < 16; ++i)
      sm.t[ty + i * 4][tx] = W[(size_t)(by * 64 + ty + i * 4) * DF + bx * 64 + tx];
    __syncthreads();
    #pragma unroll
    for (int i = 0; i < 16; ++i)                   // WT[n][k] = W[k][n]
      WT[(size_t)(bx * 64 + ty + i * 4) * DF + by * 64 + tx] =
          __float2bfloat16(sm.t[tx][ty + i * 4]);
  }
  {                                                // edges: 4 rows per wave
    const int rbase = blk * 16 + wv * 4;
    const unsigned long long lt = (1ull << lane) - 1ull;
    float4 cur[8], nxt[8];
    const float4* r4 = (const float4*)(adj + (size_t)rbase * NCOLS);
    #pragma unroll
    for (int k = 0; k < 8; ++k) cur[k] = r4[k * 64 + lane];
    for (int g = 0; g < 4; ++g) {
      const int r = rbase + g;
      if (g < 3) {
        const float4* rn = (const float4*)(adj + (size_t)(r + 1) * NCOLS);
        #pragma unroll
        for (int k = 0; k < 8; ++k) nxt[k] = rn[k * 64 + lane];
      }
      const int n = r & (NCOLS - 1);
      int base = 0;
      #pragma unroll
      for (int k = 0; k < 8; ++k) {
        const int c0 = k * 256 + lane * 4;
        const bool f0 = (cur[k].x != 0.0f) || (c0 + 0 == n);
        const bool f1 = (cur[k].y != 0.0f) || (c0 + 1 == n);
        const bool f2 = (cur[k].z != 0.0f) || (c0 + 2 == n);
        const bool f3 = (cur[k].w != 0.0f) || (c0 + 3 == n);
        const unsigned long long m0 = __ballot(f0);
        const unsigned long long m1 = __ballot(f1);
        const unsigned long long m2 = __ballot(f2);
        const unsigned long long m3 = __ballot(f3);
        const int n0 = __popcll(m0), n1 = __popcll(m1), n2 = __popcll(m2), n3 = __popcll(m3);
        if (f0) { int p = base + __popcll(m0 & lt);                if (p < CAP) edges[(size_t)r * CAP + p] = c0 + 0; }
        if (f1) { int p = base + n0 + __popcll(m1 & lt);           if (p < CAP) edges[(size_t)r * CAP + p] = c0 + 1; }
        if (f2) { int p = base + n0 + n1 + __popcll(m2 & lt);      if (p < CAP) edges[(size_t)r * CAP + p] = c0 + 2; }
        if (f3) { int p = base + n0 + n1 + n2 + __popcll(m3 & lt); if (p < CAP) edges[(size_t)r * CAP + p] = c0 + 3; }
        base += n0 + n1 + n2 + n3;
      }
      if (lane == 0) {
        cnt[r] = base < CAP ? base : CAP;
        dinv[r] = rsqrtf((float)base);             // deg >= 1 (forced self-loop)
      }
      #pragma unroll
      for (int k = 0; k < 8; ++k) cur[k] = nxt[k];
    }
  }
  grid_sync(&bar[0], tid);

  // ------------------------- Phase B: gemm 128x64 ------------------------
  {
    const int p  = blk & 127;                      // M-panel; panel -> XCD p&7
    const int nb = blk >> 7;                       // 0..7
    const int bm = p * 128;
    const int bn = nb * 64;
    const int w = wv;
    const int wm = (w >> 1) * 64;
    const int wn = (w & 1) * 32;
    const int srow = tid >> 2;                     // B staging row (0..63)
    const int scol = (tid & 3) * 8;
    const int arow = tid >> 1;                     // A staging row (0..127)
    const int akh  = (tid & 1) * 16;
    const int kl = (lane >> 4) * 8;
    const int rl = lane & 15;

    f32x4 acc[4][2] = {};
    float4 ar0, ar1, ar2, ar3;

    #define LOAD_A(k0)  do {                                                  \
      const float4* g_ = (const float4*)(X + (size_t)(bm + arow) * DF + (k0) + akh); \
      ar0 = g_[0]; ar1 = g_[1]; ar2 = g_[2]; ar3 = g_[3]; } while (0)

    #define STAGE_B(k0, buf)  do {                                            \
      const __hip_bfloat16* gb = WT + (size_t)(bn + srow) * DF + (k0) + scol;  \
      char* lb = (char*)&sm.g.Bs[buf][0] + w * 1024;                           \
      __builtin_amdgcn_global_load_lds((gvoid_t*)gb, (svoid_t*)lb, 16, 0, 0);  \
    } while (0)

    #define WRITE_A(buf)  do {                                                \
      float xs[16];                                                           \
      *(float4*)&xs[0] = ar0; *(float4*)&xs[4] = ar1;                         \
      *(float4*)&xs[8] = ar2; *(float4*)&xs[12] = ar3;                        \
      union { __hip_bfloat16 hh[16]; uint4 q[2]; } pk;                        \
      _Pragma("unroll")                                                       \
      for (int i = 0; i < 16; ++i) pk.hh[i] = __float2bfloat16(xs[i]);        \
      char* la = (char*)&sm.g.As[buf][0] + arow * 64 + akh * 2;               \
      ((uint4*)la)[0] = pk.q[0];                                              \
      ((uint4*)la)[1] = pk.q[1]; } while (0)

    LOAD_A(0);
    STAGE_B(0, 0);
    WRITE_A(0);
    __syncthreads();

    for (int t = 0; t < 16; ++t) {
      const int c_ = t & 1, nx = c_ ^ 1;
      if (t < 15) {
        LOAD_A((t + 1) * 32);
        STAGE_B((t + 1) * 32, nx);
      }
      bf16x8 af[4], bf[2];
      #pragma unroll
      for (int mi = 0; mi < 4; ++mi)
        af[mi] = *(const bf16x8*)&sm.g.As[c_][(wm + mi * 16 + rl) * 32 + kl];
      #pragma unroll
      for (int ni = 0; ni < 2; ++ni)
        bf[ni] = *(const bf16x8*)&sm.g.Bs[c_][(wn + ni * 16 + rl) * 32 + kl];
      #pragma unroll
      for (int mi = 0; mi < 4; ++mi)
        #pragma unroll
        for (int ni = 0; ni < 2; ++ni)
          acc[mi][ni] = __builtin_amdgcn_mfma_f32_16x16x32_bf16(af[mi], bf[ni], acc[mi][ni], 0, 0, 0);
      if (t < 15) WRITE_A(nx);
      __syncthreads();
    }

    const int rq = (lane >> 4) * 4;                // D: col=lane&15, row=rq+j
    #pragma unroll
    for (int mi = 0; mi < 4; ++mi)
      #pragma unroll
      for (int ni = 0; ni < 2; ++ni) {
        const int col = bn + wn + ni * 16 + rl;
        #pragma unroll
        for (int j = 0; j < 4; ++j) {
          const int row = bm + wm + mi * 16 + rq + j;
          h[(size_t)row * DF + col] = __float2bfloat16(acc[mi][ni][j]);
        }
      }
    #undef LOAD_A
    #undef STAGE_B
    #undef WRITE_A
  }
  grid_sync(&bar[1], tid);

  // ------------------------- Phase C: aggregate --------------------------
  {
    const int batch = blk & 7;                     // batch -> XCD pin
    const int q = blk >> 3;                        // 0..127
    const float4* b4 = (const float4*)bias;
    const float4 bb0 = b4[lane * 2];
    const float4 bb1 = b4[lane * 2 + 1];
    const uint4* hbase = (const uint4*)(h + (size_t)(batch << 11) * DF);
    const float* dv = dinv + (batch << 11);

    for (int g = 0; g < 4; ++g) {
      const int rn_ = q * 16 + wv * 4 + g;         // row within batch
      const int r = (batch << 11) + rn_;
      const int c = cnt[r];
      int   ml = 0;
      float wl = 0.0f;
      if (lane < c) {
        ml = edges[(size_t)r * CAP + lane];
        wl = dv[ml];
      }
      float acc[8] = {0.f, 0.f, 0.f, 0.f, 0.f, 0.f, 0.f, 0.f};
      for (int e = 0; e < c; ++e) {
        const int   m  = __shfl(ml, e);
        const float wt = __shfl(wl, e);
        const uint4 hv = hbase[(size_t)m * 64 + lane];
        acc[0] += wt * __uint_as_float(hv.x << 16);
        acc[1] += wt * __uint_as_float(hv.x & 0xffff0000u);
        acc[2] += wt * __uint_as_float(hv.y << 16);
        acc[3] += wt * __uint_as_float(hv.y & 0xffff0000u);
        acc[4] += wt * __uint_as_float(hv.z << 16);
        acc[5] += wt * __uint_as_float(hv.z & 0xffff0000u);
        acc[6] += wt * __uint_as_float(hv.w << 16);
        acc[7] += wt * __uint_as_float(hv.w & 0xffff0000u);
      }
      const float dn = dv[rn_];
      float4 o0, o1;
      o0.x = tanhf(acc[0] * dn + bb0.x);
      o0.y = tanhf(acc[1] * dn + bb0.y);
      o0.z = tanhf(acc[2] * dn + bb0.z);
      o0.w = tanhf(acc[3] * dn + bb0.w);
      o1.x = tanhf(acc[4] * dn + bb1.x);
      o1.y = tanhf(acc[5] * dn + bb1.y);
      o1.z = tanhf(acc[6] * dn + bb1.z);
      o1.w = tanhf(acc[7] * dn + bb1.w);
      float4* op = (float4*)(out + (size_t)r * DF + lane * 8);
      op[0] = o0;
      op[1] = o1;
    }
  }
}

// ---------------------------------------------------------------------------
extern "C" void kernel_launch(void* const* d_in, const int* in_sizes, int n_in,
                              void* d_out, int out_size, void* d_ws, size_t ws_size,
                              hipStream_t stream) {
  const float* X    = (const float*)d_in[0];   // [8,2048,512]
  const float* adj  = (const float*)d_in[1];   // [8,2048,2048]
  const float* W    = (const float*)d_in[2];   // [512,512]
  const float* bias = (const float*)d_in[3];   // [512]
  float* out = (float*)d_out;

  char* ws = (char*)d_ws;
  __hip_bfloat16* h    = (__hip_bfloat16*)(ws);                    // 16,777,216 B
  __hip_bfloat16* WT   = (__hip_bfloat16*)(ws + 16777216);         //    524,288 B
  float*          dinv = (float*)(ws + 17301504);                  //     65,536 B
  int*            cnt  = (int*)  (ws + 17367040);                  //     65,536 B
  int*            edges= (int*)  (ws + 17432576);                  //  4,194,304 B
  int*            bar  = (int*)  (ws + 21626880);                  //          8 B
  // total ws: 21,626,888 B

  hipMemsetAsync(bar, 0, 2 * sizeof(int), stream);   // reset grid-barrier counters
  gcn_fused<<<NBLK, 256, 0, stream>>>(X, adj, W, bias, out, h, WT, cnt, edges, dinv, bar);
}

// Round 6
// 115.315 us; speedup vs baseline: 3.5368x; 3.5368x over previous
//
#include <hip/hip_runtime.h>
#include <hip/hip_bf16.h>
#include <math.h>

// Problem: B=8, N=2048, DIN=DOUT=512, adj binary p=0.01
// out = tanh( D^-1/2 (A v I) D^-1/2 (X W) + b )
//
// MEASUREMENT ROUND: scan_wt is launched 3x (idempotent) so that
//   T = scan_cold + 2*scan_warm + gemm + agg  disambiguates scan vs gemm cost.
//
//   K1 scan_wt  x3 : blocks 0..63 = W->WT bf16; blocks 64..1087 = adj scan,
//                    per-lane nibble masks (no ballots, no predicated store
//                    storm), 16 rows/block, 2-deep row pipeline.
//   K2 gemm_k      : H = X @ W, bf16 MFMA 128x128, BK=32, dbuf, 1 barrier/step,
//                    M-panel -> XCD pinned (all 4 N-blocks share X in one L2).
//   K3 aggregate   : wave-per-row gather, batch = blk&7 -> XCD pin (FIXED:
//                    block-indexed, was wave-indexed in R3/R4).

#define NROWS 16384
#define NCOLS 2048
#define DF    512
#define CAP   64        // max edges/row (Binom(2048,0.01): mean ~21.5, P(>=64)~0)

typedef __attribute__((ext_vector_type(8))) short bf16x8;
typedef __attribute__((ext_vector_type(4))) float f32x4;
typedef const void __attribute__((address_space(1))) gvoid_t;
typedef void __attribute__((address_space(3))) svoid_t;

// ---------------------------------------------------------------------------
// K1: blocks [0,64) W->WT; blocks [64,1088) adjacency scan, 16 rows each.
// Lane l owns columns {k*256 + l*4 + j : k<8, j<4} of its row.
// ---------------------------------------------------------------------------
__global__ __launch_bounds__(256) void scan_wt(
    const float* __restrict__ W, __hip_bfloat16* __restrict__ WT,
    const float* __restrict__ adj, int* __restrict__ cnt,
    int* __restrict__ edges, float* __restrict__ dinv) {
  __shared__ float t[64][65];
  const int blk = blockIdx.x;
  const int tid = threadIdx.x;
  if (blk < 64) {                                  // W -> W^T bf16
    const int bx = blk & 7, by = blk >> 3;
    const int tx = tid & 63, ty = tid >> 6;
    #pragma unroll
    for (int i = 0; i < 16; ++i)
      t[ty + i * 4][tx] = W[(size_t)(by * 64 + ty + i * 4) * DF + bx * 64 + tx];
    __syncthreads();
    #pragma unroll
    for (int i = 0; i < 16; ++i)                   // WT[n][k] = W[k][n]
      WT[(size_t)(bx * 64 + ty + i * 4) * DF + by * 64 + tx] =
          __float2bfloat16(t[tx][ty + i * 4]);
    return;
  }
  const int lane = tid & 63;
  const int wv = tid >> 6;
  const int rbase = (blk - 64) * 16 + wv * 4;      // 4 rows per wave
  float4 cur[8], nxt[8];
  {
    const float4* r4 = (const float4*)(adj + (size_t)rbase * NCOLS);
    #pragma unroll
    for (int k = 0; k < 8; ++k) cur[k] = r4[k * 64 + lane];
  }
  #pragma unroll
  for (int g = 0; g < 4; ++g) {
    const int r = rbase + g;
    if (g < 3) {
      const float4* rn = (const float4*)(adj + (size_t)(r + 1) * NCOLS);
      #pragma unroll
      for (int k = 0; k < 8; ++k) nxt[k] = rn[k * 64 + lane];
    }
    const int n = r & (NCOLS - 1);
    unsigned m = 0;
    #pragma unroll
    for (int k = 0; k < 8; ++k) {
      m |= (cur[k].x != 0.0f ? 1u : 0u) << (4 * k);
      m |= (cur[k].y != 0.0f ? 1u : 0u) << (4 * k + 1);
      m |= (cur[k].z != 0.0f ? 1u : 0u) << (4 * k + 2);
      m |= (cur[k].w != 0.0f ? 1u : 0u) << (4 * k + 3);
    }
    if (lane == ((n >> 2) & 63))                   // force self-loop bit
      m |= 1u << (((n >> 8) << 2) | (n & 3));
    const int c_ = __popc(m);
    int inc = c_;                                  // inclusive wave prefix-scan
    #pragma unroll
    for (int off = 1; off < 64; off <<= 1) {
      const int tv = __shfl_up(inc, off);
      if (lane >= off) inc += tv;
    }
    const int tot = __shfl(inc, 63);
    int p = inc - c_;                              // exclusive prefix
    unsigned mm = m;
    const size_t eb = (size_t)r * CAP;
    while (mm) {                                   // <= ~3 iters per lane
      const int bpos = __ffs(mm) - 1;
      mm &= mm - 1;
      if (p < CAP)
        edges[eb + p] = ((bpos >> 2) << 8) + (lane << 2) + (bpos & 3);
      ++p;
    }
    if (lane == 63) {
      cnt[r] = tot < CAP ? tot : CAP;
      dinv[r] = rsqrtf((float)tot);                // deg >= 1 (self-loop)
    }
    #pragma unroll
    for (int k = 0; k < 8; ++k) cur[k] = nxt[k];
  }
}

// ---------------------------------------------------------------------------
// K2: H = X @ WT^T. 128x128 tile, BK=32, 4 waves (2x2), double-buffered LDS,
//     one barrier per K-step. B via global_load_lds DMA; A reg-staged
//     fp32->bf16 (loads issued one phase early, ds_write after MFMA).
//     Panel->XCD: ids sharing an M-panel are congruent mod 8.
// ---------------------------------------------------------------------------
__global__ __launch_bounds__(256) void gemm_k(
    const float* __restrict__ X, const __hip_bfloat16* __restrict__ WT,
    __hip_bfloat16* __restrict__ H) {
  __shared__ __hip_bfloat16 As[2][128 * 32];       // 2 x 8 KB  [row][k]
  __shared__ __hip_bfloat16 Bs[2][128 * 32];       // 2 x 8 KB  [n][k]
  const int tid = threadIdx.x;
  const int lane = tid & 63;
  const int w = tid >> 6;
  const int id = blockIdx.x;
  const int xcd = id & 7;
  const int jj = id >> 3;                          // 0..63
  const int bm = (xcd * 16 + (jj >> 2)) * 128;     // panel id%8-constant -> XCD
  const int bn = (jj & 3) * 128;

  const int wm = (w >> 1) * 64;
  const int wn = (w & 1) * 64;
  const int srow = tid >> 2;                       // B staging row (0..63)
  const int scol = (tid & 3) * 8;
  const int arow = tid >> 1;                       // A staging row (0..127)
  const int akh  = (tid & 1) * 16;
  const int kl = (lane >> 4) * 8;
  const int rl = lane & 15;

  f32x4 acc[4][4] = {};
  float4 ar0, ar1, ar2, ar3;

  #define LOAD_A(k0)  do {                                              \
    const float4* g_ = (const float4*)(X + (size_t)(bm + arow) * DF + (k0) + akh); \
    ar0 = g_[0]; ar1 = g_[1]; ar2 = g_[2]; ar3 = g_[3]; } while (0)

  #define STAGE_B(k0, buf)  do {                                        \
    _Pragma("unroll")                                                   \
    for (int i = 0; i < 2; ++i) {                                       \
      const __hip_bfloat16* gb = WT + (size_t)(bn + i * 64 + srow) * DF + (k0) + scol; \
      char* lb = (char*)&Bs[buf][0] + i * 4096 + w * 1024;              \
      __builtin_amdgcn_global_load_lds((gvoid_t*)gb, (svoid_t*)lb, 16, 0, 0); \
    } } while (0)

  #define WRITE_A(buf)  do {                                            \
    float xs[16];                                                       \
    *(float4*)&xs[0] = ar0; *(float4*)&xs[4] = ar1;                     \
    *(float4*)&xs[8] = ar2; *(float4*)&xs[12] = ar3;                    \
    union { __hip_bfloat16 hh[16]; uint4 q[2]; } pk;                    \
    _Pragma("unroll")                                                   \
    for (int i = 0; i < 16; ++i) pk.hh[i] = __float2bfloat16(xs[i]);    \
    char* la = (char*)&As[buf][0] + arow * 64 + akh * 2;                \
    ((uint4*)la)[0] = pk.q[0];                                          \
    ((uint4*)la)[1] = pk.q[1]; } while (0)

  LOAD_A(0);
  STAGE_B(0, 0);
  WRITE_A(0);
  __syncthreads();

  for (int tIt = 0; tIt < 16; ++tIt) {
    const int c_ = tIt & 1, nx = c_ ^ 1;
    if (tIt < 15) {
      LOAD_A((tIt + 1) * 32);
      STAGE_B((tIt + 1) * 32, nx);
    }
    bf16x8 af[4], bf[4];
    #pragma unroll
    for (int mi = 0; mi < 4; ++mi)
      af[mi] = *(const bf16x8*)&As[c_][(wm + mi * 16 + rl) * 32 + kl];
    #pragma unroll
    for (int ni = 0; ni < 4; ++ni)
      bf[ni] = *(const bf16x8*)&Bs[c_][(wn + ni * 16 + rl) * 32 + kl];
    #pragma unroll
    for (int mi = 0; mi < 4; ++mi)
      #pragma unroll
      for (int ni = 0; ni < 4; ++ni)
        acc[mi][ni] = __builtin_amdgcn_mfma_f32_16x16x32_bf16(af[mi], bf[ni], acc[mi][ni], 0, 0, 0);
    if (tIt < 15) WRITE_A(nx);
    __syncthreads();
  }

  const int rq = (lane >> 4) * 4;                  // D: col=lane&15, row=rq+j
  #pragma unroll
  for (int mi = 0; mi < 4; ++mi)
    #pragma unroll
    for (int ni = 0; ni < 4; ++ni) {
      const int col = bn + wn + ni * 16 + rl;
      #pragma unroll
      for (int j = 0; j < 4; ++j) {
        const int row = bm + wm + mi * 16 + rq + j;
        H[(size_t)row * DF + col] = __float2bfloat16(acc[mi][ni][j]);
      }
    }
  #undef LOAD_A
  #undef STAGE_B
  #undef WRITE_A
}

// ---------------------------------------------------------------------------
// K3: wave-per-row gather. batch = blk&7 -> XCD pin (block-indexed, fixed).
// Each batch's 2MB bf16 h-slice stays resident in its XCD's 4MB L2.
// ---------------------------------------------------------------------------
__global__ __launch_bounds__(256) void aggregate(
    const __hip_bfloat16* __restrict__ h, const int* __restrict__ cnt,
    const int* __restrict__ edges, const float* __restrict__ dinv,
    const float* __restrict__ bias, float* __restrict__ out) {
  const int lane = threadIdx.x & 63;
  const int wv = threadIdx.x >> 6;
  const int batch = blockIdx.x & 7;                // -> XCD pin
  const int q = blockIdx.x >> 3;                   // 0..511
  const int rn_ = q * 4 + wv;                      // row within batch
  const int r = (batch << 11) + rn_;
  const int c = cnt[r];
  int   ml = 0;
  float wl = 0.0f;
  if (lane < c) {
    ml = edges[(size_t)r * CAP + lane];
    wl = dinv[(batch << 11) + ml];
  }
  const float4* b4 = (const float4*)bias;
  const float4 bb0 = b4[lane * 2];
  const float4 bb1 = b4[lane * 2 + 1];

  float acc[8] = {0.f, 0.f, 0.f, 0.f, 0.f, 0.f, 0.f, 0.f};
  const uint4* hbase = (const uint4*)(h + (size_t)(batch << 11) * DF);
  for (int e = 0; e < c; ++e) {
    const int   m  = __shfl(ml, e);
    const float wt = __shfl(wl, e);
    const uint4 hv = hbase[(size_t)m * 64 + lane];
    acc[0] += wt * __uint_as_float(hv.x << 16);
    acc[1] += wt * __uint_as_float(hv.x & 0xffff0000u);
    acc[2] += wt * __uint_as_float(hv.y << 16);
    acc[3] += wt * __uint_as_float(hv.y & 0xffff0000u);
    acc[4] += wt * __uint_as_float(hv.z << 16);
    acc[5] += wt * __uint_as_float(hv.z & 0xffff0000u);
    acc[6] += wt * __uint_as_float(hv.w << 16);
    acc[7] += wt * __uint_as_float(hv.w & 0xffff0000u);
  }
  const float dn = dinv[r];
  float4 o0, o1;
  o0.x = tanhf(acc[0] * dn + bb0.x);
  o0.y = tanhf(acc[1] * dn + bb0.y);
  o0.z = tanhf(acc[2] * dn + bb0.z);
  o0.w = tanhf(acc[3] * dn + bb0.w);
  o1.x = tanhf(acc[4] * dn + bb1.x);
  o1.y = tanhf(acc[5] * dn + bb1.y);
  o1.z = tanhf(acc[6] * dn + bb1.z);
  o1.w = tanhf(acc[7] * dn + bb1.w);
  float4* op = (float4*)(out + (size_t)r * DF + lane * 8);
  op[0] = o0;
  op[1] = o1;
}

// ---------------------------------------------------------------------------
extern "C" void kernel_launch(void* const* d_in, const int* in_sizes, int n_in,
                              void* d_out, int out_size, void* d_ws, size_t ws_size,
                              hipStream_t stream) {
  const float* X    = (const float*)d_in[0];   // [8,2048,512]
  const float* adj  = (const float*)d_in[1];   // [8,2048,2048]
  const float* W    = (const float*)d_in[2];   // [512,512]
  const float* bias = (const float*)d_in[3];   // [512]
  float* out = (float*)d_out;

  char* ws = (char*)d_ws;
  __hip_bfloat16* h    = (__hip_bfloat16*)(ws);                    // 16,777,216 B
  __hip_bfloat16* WT   = (__hip_bfloat16*)(ws + 16777216);         //    524,288 B
  float*          dinv = (float*)(ws + 17301504);                  //     65,536 B
  int*            cnt  = (int*)  (ws + 17367040);                  //     65,536 B
  int*            edges= (int*)  (ws + 17432576);                  //  4,194,304 B
  // total ws: 21,626,880 B

  // 3x identical (idempotent) scan launches: timing decomposition.
  scan_wt<<<64 + 1024, 256, 0, stream>>>(W, WT, adj, cnt, edges, dinv);
  scan_wt<<<64 + 1024, 256, 0, stream>>>(W, WT, adj, cnt, edges, dinv);
  scan_wt<<<64 + 1024, 256, 0, stream>>>(W, WT, adj, cnt, edges, dinv);
  gemm_k<<<512, 256, 0, stream>>>(X, WT, h);
  aggregate<<<NROWS / 4, 256, 0, stream>>>(h, cnt, edges, dinv, bias, out);
}

// Round 7
// 82.217 us; speedup vs baseline: 4.9607x; 1.4026x over previous
//
#include <hip/hip_runtime.h>
#include <hip/hip_bf16.h>
#include <math.h>

// Problem: B=8, N=2048, DIN=DOUT=512, adj binary p=0.01
// out = tanh( D^-1/2 (A v I) D^-1/2 (X W) + b )
//
//   K1 scan_wt_cvt : blk[0,64)=W->WT bf16; blk[64,1088)=adj scan (16 rows/blk,
//                    nibble masks + wave prefix scan); blk[1088,3136)=X->bf16.
//   K2 gemm_k      : H = Xb @ WT^T, all-bf16 MFMA 128x128, BK=32, dbuf LDS,
//                    global_load_lds both operands, 1 barrier/step,
//                    M-panel -> XCD pinned.
//   K3 aggregate   : 2 rows/wave, chunk-4 gathers (8 loads in flight),
//                    batch = blk&7 -> XCD pin (2MB h slice per L2).

#define NROWS 16384
#define NCOLS 2048
#define DF    512
#define CAP   64        // max edges/row (Binom(2048,0.01): mean ~21.5, P(>=64)~0)

typedef __attribute__((ext_vector_type(8))) short bf16x8;
typedef __attribute__((ext_vector_type(4))) float f32x4;
typedef const void __attribute__((address_space(1))) gvoid_t;
typedef void __attribute__((address_space(3))) svoid_t;

// ---------------------------------------------------------------------------
// K1: W->WT | adj scan | X->bf16
// ---------------------------------------------------------------------------
__global__ __launch_bounds__(256) void scan_wt_cvt(
    const float* __restrict__ W, __hip_bfloat16* __restrict__ WT,
    const float* __restrict__ adj, int* __restrict__ cnt,
    int* __restrict__ edges, float* __restrict__ dinv,
    const float* __restrict__ X, __hip_bfloat16* __restrict__ Xb) {
  __shared__ float t[64][65];
  const int blk = blockIdx.x;
  const int tid = threadIdx.x;
  if (blk < 64) {                                  // W -> W^T bf16
    const int bx = blk & 7, by = blk >> 3;
    const int tx = tid & 63, ty = tid >> 6;
    #pragma unroll
    for (int i = 0; i < 16; ++i)
      t[ty + i * 4][tx] = W[(size_t)(by * 64 + ty + i * 4) * DF + bx * 64 + tx];
    __syncthreads();
    #pragma unroll
    for (int i = 0; i < 16; ++i)                   // WT[n][k] = W[k][n]
      WT[(size_t)(bx * 64 + ty + i * 4) * DF + by * 64 + tx] =
          __float2bfloat16(t[tx][ty + i * 4]);
    return;
  }
  if (blk >= 1088) {                               // X -> bf16 (coalesced)
    const int b = blk - 1088;                      // 0..2047
    const float4* X4 = (const float4*)X;
    ushort4* O4 = (ushort4*)Xb;
    #pragma unroll
    for (int i = 0; i < 4; ++i) {
      const int idx = b * 1024 + i * 256 + tid;
      const float4 v = X4[idx];
      union { ushort4 u; __hip_bfloat16 h[4]; } p;
      p.h[0] = __float2bfloat16(v.x);
      p.h[1] = __float2bfloat16(v.y);
      p.h[2] = __float2bfloat16(v.z);
      p.h[3] = __float2bfloat16(v.w);
      O4[idx] = p.u;
    }
    return;
  }
  // adjacency scan: 16 rows per block, 4 rows per wave, 2-deep pipeline
  const int lane = tid & 63;
  const int wv = tid >> 6;
  const int rbase = (blk - 64) * 16 + wv * 4;
  float4 cur[8], nxt[8];
  {
    const float4* r4 = (const float4*)(adj + (size_t)rbase * NCOLS);
    #pragma unroll
    for (int k = 0; k < 8; ++k) cur[k] = r4[k * 64 + lane];
  }
  #pragma unroll
  for (int g = 0; g < 4; ++g) {
    const int r = rbase + g;
    if (g < 3) {
      const float4* rn = (const float4*)(adj + (size_t)(r + 1) * NCOLS);
      #pragma unroll
      for (int k = 0; k < 8; ++k) nxt[k] = rn[k * 64 + lane];
    }
    const int n = r & (NCOLS - 1);
    unsigned m = 0;
    #pragma unroll
    for (int k = 0; k < 8; ++k) {
      m |= (cur[k].x != 0.0f ? 1u : 0u) << (4 * k);
      m |= (cur[k].y != 0.0f ? 1u : 0u) << (4 * k + 1);
      m |= (cur[k].z != 0.0f ? 1u : 0u) << (4 * k + 2);
      m |= (cur[k].w != 0.0f ? 1u : 0u) << (4 * k + 3);
    }
    if (lane == ((n >> 2) & 63))                   // force self-loop bit
      m |= 1u << (((n >> 8) << 2) | (n & 3));
    const int c_ = __popc(m);
    int inc = c_;                                  // inclusive wave prefix-scan
    #pragma unroll
    for (int off = 1; off < 64; off <<= 1) {
      const int tv = __shfl_up(inc, off);
      if (lane >= off) inc += tv;
    }
    const int tot = __shfl(inc, 63);
    int p = inc - c_;                              // exclusive prefix
    unsigned mm = m;
    const size_t eb = (size_t)r * CAP;
    while (mm) {                                   // <= ~3 iters per lane
      const int bpos = __ffs(mm) - 1;
      mm &= mm - 1;
      if (p < CAP)
        edges[eb + p] = ((bpos >> 2) << 8) + (lane << 2) + (bpos & 3);
      ++p;
    }
    if (lane == 63) {
      cnt[r] = tot < CAP ? tot : CAP;
      dinv[r] = rsqrtf((float)tot);                // deg >= 1 (self-loop)
    }
    #pragma unroll
    for (int k = 0; k < 8; ++k) cur[k] = nxt[k];
  }
}

// ---------------------------------------------------------------------------
// K2: H = Xb @ WT^T. 128x128 tile, BK=32, 4 waves (2x2), double-buffered LDS,
//     both operands via global_load_lds, one barrier per K-step.
//     Panel->XCD: the 4 N-blocks of an M-panel are congruent mod 8.
// ---------------------------------------------------------------------------
__global__ __launch_bounds__(256) void gemm_k(
    const __hip_bfloat16* __restrict__ A, const __hip_bfloat16* __restrict__ BT,
    __hip_bfloat16* __restrict__ H) {
  __shared__ __hip_bfloat16 As[2][128 * 32];       // 2 x 8 KB  [row][k]
  __shared__ __hip_bfloat16 Bs[2][128 * 32];       // 2 x 8 KB  [n][k]
  const int tid = threadIdx.x;
  const int lane = tid & 63;
  const int w = tid >> 6;
  const int id = blockIdx.x;
  const int xcd = id & 7;
  const int jj = id >> 3;                          // 0..63
  const int bm = (xcd * 16 + (jj >> 2)) * 128;     // panel -> XCD pin
  const int bn = (jj & 3) * 128;

  const int wm = (w >> 1) * 64;
  const int wn = (w & 1) * 64;
  const int srow = tid >> 2;                       // staging row (0..63)
  const int scol = (tid & 3) * 8;
  const int kl = (lane >> 4) * 8;
  const int rl = lane & 15;

  f32x4 acc[4][4] = {};

  #define STAGE(k0, buf)  do {                                          \
    _Pragma("unroll")                                                   \
    for (int i = 0; i < 2; ++i) {                                       \
      const __hip_bfloat16* ga = A  + (size_t)(bm + i * 64 + srow) * DF + (k0) + scol; \
      const __hip_bfloat16* gb = BT + (size_t)(bn + i * 64 + srow) * DF + (k0) + scol; \
      char* la = (char*)&As[buf][0] + i * 4096 + w * 1024;              \
      char* lb = (char*)&Bs[buf][0] + i * 4096 + w * 1024;              \
      __builtin_amdgcn_global_load_lds((gvoid_t*)ga, (svoid_t*)la, 16, 0, 0); \
      __builtin_amdgcn_global_load_lds((gvoid_t*)gb, (svoid_t*)lb, 16, 0, 0); \
    } } while (0)

  STAGE(0, 0);
  __syncthreads();

  for (int tIt = 0; tIt < 16; ++tIt) {
    const int c_ = tIt & 1, nx = c_ ^ 1;
    if (tIt < 15) STAGE((tIt + 1) * 32, nx);       // prefetch next K-tile
    bf16x8 af[4], bf[4];
    #pragma unroll
    for (int mi = 0; mi < 4; ++mi)
      af[mi] = *(const bf16x8*)&As[c_][(wm + mi * 16 + rl) * 32 + kl];
    #pragma unroll
    for (int ni = 0; ni < 4; ++ni)
      bf[ni] = *(const bf16x8*)&Bs[c_][(wn + ni * 16 + rl) * 32 + kl];
    #pragma unroll
    for (int mi = 0; mi < 4; ++mi)
      #pragma unroll
      for (int ni = 0; ni < 4; ++ni)
        acc[mi][ni] = __builtin_amdgcn_mfma_f32_16x16x32_bf16(af[mi], bf[ni], acc[mi][ni], 0, 0, 0);
    __syncthreads();                               // drains next-tile DMA
  }

  const int rq = (lane >> 4) * 4;                  // D: col=lane&15, row=rq+j
  #pragma unroll
  for (int mi = 0; mi < 4; ++mi)
    #pragma unroll
    for (int ni = 0; ni < 4; ++ni) {
      const int col = bn + wn + ni * 16 + rl;
      #pragma unroll
      for (int j = 0; j < 4; ++j) {
        const int row = bm + wm + mi * 16 + rq + j;
        H[(size_t)row * DF + col] = __float2bfloat16(acc[mi][ni][j]);
      }
    }
  #undef STAGE
}

// ---------------------------------------------------------------------------
// K3: aggregate. 2048 blocks; batch = blk&7 -> XCD pin; 8 rows/block,
// 2 rows per wave, chunk-4 gathers -> 8 independent loads in flight.
// ---------------------------------------------------------------------------
__global__ __launch_bounds__(256) void aggregate(
    const __hip_bfloat16* __restrict__ h, const int* __restrict__ cnt,
    const int* __restrict__ edges, const float* __restrict__ dinv,
    const float* __restrict__ bias, float* __restrict__ out) {
  const int lane = threadIdx.x & 63;
  const int wv = threadIdx.x >> 6;
  const int batch = blockIdx.x & 7;                // -> XCD pin
  const int qb = blockIdx.x >> 3;                  // 0..255
  const int r0n = qb * 8 + wv * 2;                 // rows r0n, r0n+1
  const int r0 = (batch << 11) + r0n;
  const int r1 = r0 + 1;
  const float* dv = dinv + (batch << 11);
  const uint4* hbase = (const uint4*)(h + (size_t)(batch << 11) * DF);

  const int c0 = cnt[r0], c1 = cnt[r1];
  int   ml0 = 0, ml1 = 0;
  float wl0 = 0.0f, wl1 = 0.0f;
  if (lane < c0) { ml0 = edges[(size_t)r0 * CAP + lane]; wl0 = dv[ml0]; }
  if (lane < c1) { ml1 = edges[(size_t)r1 * CAP + lane]; wl1 = dv[ml1]; }

  float a0[8] = {0.f,0.f,0.f,0.f,0.f,0.f,0.f,0.f};
  float a1[8] = {0.f,0.f,0.f,0.f,0.f,0.f,0.f,0.f};
  const int cmax = c0 > c1 ? c0 : c1;
  for (int e = 0; e < cmax; e += 4) {
    uint4 v0[4], v1[4];
    #pragma unroll
    for (int j = 0; j < 4; ++j) {                  // issue up to 8 loads
      if (e + j < c0) v0[j] = hbase[(size_t)__shfl(ml0, e + j) * 64 + lane];
      if (e + j < c1) v1[j] = hbase[(size_t)__shfl(ml1, e + j) * 64 + lane];
    }
    #pragma unroll
    for (int j = 0; j < 4; ++j) {
      if (e + j < c0) {
        const float wt = __shfl(wl0, e + j);
        a0[0] += wt * __uint_as_float(v0[j].x << 16);
        a0[1] += wt * __uint_as_float(v0[j].x & 0xffff0000u);
        a0[2] += wt * __uint_as_float(v0[j].y << 16);
        a0[3] += wt * __uint_as_float(v0[j].y & 0xffff0000u);
        a0[4] += wt * __uint_as_float(v0[j].z << 16);
        a0[5] += wt * __uint_as_float(v0[j].z & 0xffff0000u);
        a0[6] += wt * __uint_as_float(v0[j].w << 16);
        a0[7] += wt * __uint_as_float(v0[j].w & 0xffff0000u);
      }
      if (e + j < c1) {
        const float wt = __shfl(wl1, e + j);
        a1[0] += wt * __uint_as_float(v1[j].x << 16);
        a1[1] += wt * __uint_as_float(v1[j].x & 0xffff0000u);
        a1[2] += wt * __uint_as_float(v1[j].y << 16);
        a1[3] += wt * __uint_as_float(v1[j].y & 0xffff0000u);
        a1[4] += wt * __uint_as_float(v1[j].z << 16);
        a1[5] += wt * __uint_as_float(v1[j].z & 0xffff0000u);
        a1[6] += wt * __uint_as_float(v1[j].w << 16);
        a1[7] += wt * __uint_as_float(v1[j].w & 0xffff0000u);
      }
    }
  }
  const float4* b4 = (const float4*)bias;
  const float4 bb0 = b4[lane * 2];
  const float4 bb1 = b4[lane * 2 + 1];
  const float dn0 = dv[r0n], dn1 = dv[r0n + 1];
  float4 o;
  float* op0 = out + (size_t)r0 * DF + lane * 8;
  o.x = tanhf(a0[0] * dn0 + bb0.x); o.y = tanhf(a0[1] * dn0 + bb0.y);
  o.z = tanhf(a0[2] * dn0 + bb0.z); o.w = tanhf(a0[3] * dn0 + bb0.w);
  *(float4*)op0 = o;
  o.x = tanhf(a0[4] * dn0 + bb1.x); o.y = tanhf(a0[5] * dn0 + bb1.y);
  o.z = tanhf(a0[6] * dn0 + bb1.z); o.w = tanhf(a0[7] * dn0 + bb1.w);
  *(float4*)(op0 + 4) = o;
  float* op1 = out + (size_t)r1 * DF + lane * 8;
  o.x = tanhf(a1[0] * dn1 + bb0.x); o.y = tanhf(a1[1] * dn1 + bb0.y);
  o.z = tanhf(a1[2] * dn1 + bb0.z); o.w = tanhf(a1[3] * dn1 + bb0.w);
  *(float4*)op1 = o;
  o.x = tanhf(a1[4] * dn1 + bb1.x); o.y = tanhf(a1[5] * dn1 + bb1.y);
  o.z = tanhf(a1[6] * dn1 + bb1.z); o.w = tanhf(a1[7] * dn1 + bb1.w);
  *(float4*)(op1 + 4) = o;
}

// ---------------------------------------------------------------------------
extern "C" void kernel_launch(void* const* d_in, const int* in_sizes, int n_in,
                              void* d_out, int out_size, void* d_ws, size_t ws_size,
                              hipStream_t stream) {
  const float* X    = (const float*)d_in[0];   // [8,2048,512]
  const float* adj  = (const float*)d_in[1];   // [8,2048,2048]
  const float* W    = (const float*)d_in[2];   // [512,512]
  const float* bias = (const float*)d_in[3];   // [512]
  float* out = (float*)d_out;

  char* ws = (char*)d_ws;
  __hip_bfloat16* h    = (__hip_bfloat16*)(ws);                    // 16,777,216 B
  __hip_bfloat16* WT   = (__hip_bfloat16*)(ws + 16777216);         //    524,288 B
  float*          dinv = (float*)(ws + 17301504);                  //     65,536 B
  int*            cnt  = (int*)  (ws + 17367040);                  //     65,536 B
  int*            edges= (int*)  (ws + 17432576);                  //  4,194,304 B
  __hip_bfloat16* Xb   = (__hip_bfloat16*)(ws + 21626880);         // 16,777,216 B
  // total ws: 38,404,096 B

  scan_wt_cvt<<<3136, 256, 0, stream>>>(W, WT, adj, cnt, edges, dinv, X, Xb);
  gemm_k<<<512, 256, 0, stream>>>(Xb, WT, h);
  aggregate<<<2048, 256, 0, stream>>>(h, cnt, edges, dinv, bias, out);
}